// Round 1
// 248.304 us; speedup vs baseline: 1.0839x; 1.0839x over previous
//
#include <hip/hip_runtime.h>
#include <hip/hip_bf16.h>

#define M_DIM 12608   // 64*197
#define K_DIM 768
#define N_DIM 3072
#define M_PAD 12800   // 50*256
#define BM 256
#define BN 256
#define BK 32
#define NT (K_DIM / BK)     // 24 K-tiles
#define MBLK (M_PAD / BM)   // 50
#define NBLK_N (N_DIM / BN) // 12
#define NWG (MBLK * NBLK_N) // 600, divisible by 8

typedef __attribute__((ext_vector_type(8))) short bf16x8;
typedef __attribute__((ext_vector_type(4))) float f32x4;

__device__ __forceinline__ void gload_lds16(const void* g, void* l) {
  __builtin_amdgcn_global_load_lds(
      (const __attribute__((address_space(1))) unsigned int*)g,
      (__attribute__((address_space(3))) unsigned int*)l,
      16, 0, 0);
}

// Fused convert: blocks [0, GX) do x fp32->bf16 (+M_PAD zero tail),
// blocks [GX, GX+GW) do 2:4 mask + w fp32->bf16.
#define GX 4800   // M_PAD*K/8/256
#define GW 2304   // N*(K/4)/256
__global__ void cvt_fused(const float* __restrict__ x, const float* __restrict__ w,
                          __hip_bfloat16* __restrict__ xb, __hip_bfloat16* __restrict__ wb) {
  if (blockIdx.x < GX) {
    size_t i = ((size_t)blockIdx.x * 256 + threadIdx.x) * 8;
    union { __hip_bfloat16 h[8]; uint4 u; } o;
    if (i < (size_t)M_DIM * K_DIM) {
      float4 a = *(const float4*)(x + i);
      float4 b = *(const float4*)(x + i + 4);
      o.h[0] = __float2bfloat16(a.x); o.h[1] = __float2bfloat16(a.y);
      o.h[2] = __float2bfloat16(a.z); o.h[3] = __float2bfloat16(a.w);
      o.h[4] = __float2bfloat16(b.x); o.h[5] = __float2bfloat16(b.y);
      o.h[6] = __float2bfloat16(b.z); o.h[7] = __float2bfloat16(b.w);
    } else {
      o.u = make_uint4(0, 0, 0, 0);
    }
    *(uint4*)(xb + i) = o.u;
  } else {
    size_t g = ((size_t)(blockIdx.x - GX) * 256 + threadIdx.x);
    float4 v = *(const float4*)(w + g * 4);
    float val[4] = {v.x, v.y, v.z, v.w};
    float a[4] = {fabsf(v.x), fabsf(v.y), fabsf(v.z), fabsf(v.w)};
    union { __hip_bfloat16 h[4]; uint2 u; } o;
#pragma unroll
    for (int i = 0; i < 4; ++i) {
      int rank = 0;
#pragma unroll
      for (int j = 0; j < 4; ++j)
        rank += (a[j] > a[i]) || (a[j] == a[i] && j > i);
      o.h[i] = __float2bfloat16(rank < 2 ? val[i] : 0.0f);
    }
    *(uint2*)(wb + g * 4) = o.u;
  }
}

// 256x256 tile, BK=32, 8 waves (2Mx4N), per-wave 128x64 output (8x4 MFMA frags).
// 4-deep LDS K-tile pipeline (4 x 32KB = 128KB dynamic LDS), counted vmcnt(4)
// once per K-tile, raw s_barrier (no drain), setprio around MFMA clusters.
//
// LDS buffer q at q*32768: A 256x32 bf16 (16KB) then B 256x32 (16KB).
// Element (row, kg) at byte row*64 + (kg ^ (row&3) ^ ((row>>2)&3))*16.
// Staging: gload_lds writes linearly (wave-uniform base + lane*16); the swizzle
// is applied by pre-swizzling the per-lane GLOBAL source k-group (rule #21).
__global__ __launch_bounds__(512, 2) void gemm_8p(
    const __hip_bfloat16* __restrict__ A,   // [M_PAD][K]
    const __hip_bfloat16* __restrict__ B,   // [N][K]
    const float* __restrict__ bias,         // [N]
    float* __restrict__ C)                  // [M][N]
{
  extern __shared__ char smem[];

  const int tid  = threadIdx.x;
  const int lane = tid & 63;
  const int wave = tid >> 6;
  const int wm   = wave >> 2;   // 0..1  (M half)
  const int wn   = wave & 3;    // 0..3  (N quarter)

  // bijective XCD swizzle: 600 = 8 * 75; consecutive swz iterate N fastest
  const int wg  = blockIdx.x;
  const int swz = (wg & 7) * (NWG / 8) + (wg >> 3);
  const int tile_m = (swz / NBLK_N) * BM;
  const int tile_n = (swz % NBLK_N) * BN;

  // ---- staging geometry: one gload issue = 8 waves x 16 rows x 64B (8KB)
  // lane l -> row r2 = l>>2, physical slot p = l&3; global k-group = p ^ f(row)
  const int r2 = lane >> 2;
  const int p  = lane & 3;
  const int fxor = (r2 & 3) ^ ((r2 >> 2) & 3);   // == f(row) for row = u*128+wave*16+r2
  const int gsw  = p ^ fxor;
  const __hip_bfloat16* asrc[2];
  const __hip_bfloat16* bsrc[2];
#pragma unroll
  for (int u = 0; u < 2; ++u) {
    const int row = u * 128 + wave * 16 + r2;
    asrc[u] = A + (size_t)(tile_m + row) * K_DIM + gsw * 8;
    bsrc[u] = B + (size_t)(tile_n + row) * K_DIM + gsw * 8;
  }

  // ---- fragment read geometry (A/B operand: row = lane&15, k-group = lane>>4)
  const int frow  = lane & 15;
  const int fslot = (lane >> 4) ^ (frow & 3) ^ ((frow >> 2) & 3);
  const int abase = (wm * 128 + frow) * 64 + fslot * 16;            // + q*32768 + m*1024
  const int bbase = 16384 + (wn * 64 + frow) * 64 + fslot * 16;     // + q*32768 + n*1024

  f32x4 acc[8][4] = {};

  // ---- prologue: stage K-tiles 0 and 1 (order: A0,A0',B0,B0',A1,A1',B1,B1')
#pragma unroll
  for (int u = 0; u < 2; ++u)
    gload_lds16(asrc[u], smem + u * 8192 + wave * 1024);
#pragma unroll
  for (int u = 0; u < 2; ++u)
    gload_lds16(bsrc[u], smem + 16384 + u * 8192 + wave * 1024);
#pragma unroll
  for (int u = 0; u < 2; ++u)
    gload_lds16(asrc[u] + BK, smem + 32768 + u * 8192 + wave * 1024);
#pragma unroll
  for (int u = 0; u < 2; ++u)
    gload_lds16(bsrc[u] + BK, smem + 32768 + 16384 + u * 8192 + wave * 1024);
  asm volatile("s_waitcnt vmcnt(4)" ::: "memory");   // tile 0 resident; tile 1 in flight
  __builtin_amdgcn_s_barrier();

  // ---- main loop: tile t from buf (t&3); stage tile t+2 into buf ((t+2)&3)
#pragma unroll
  for (int t = 0; t < NT; ++t) {
    const int q  = t & 3;
    const int qs = (t + 2) & 3;
    const char* bq = smem + q * 32768;

    // phase 1: M-half 0
    bf16x8 af[4], bfv[4];
#pragma unroll
    for (int m = 0; m < 4; ++m)
      af[m] = *(const bf16x8*)(bq + abase + m * 1024);
#pragma unroll
    for (int n = 0; n < 4; ++n)
      bfv[n] = *(const bf16x8*)(bq + bbase + n * 1024);
    if (t + 2 < NT) {
#pragma unroll
      for (int u = 0; u < 2; ++u)
        gload_lds16(asrc[u] + (t + 2) * BK, smem + qs * 32768 + u * 8192 + wave * 1024);
    }
    __builtin_amdgcn_s_barrier();
    __builtin_amdgcn_s_setprio(1);
#pragma unroll
    for (int m = 0; m < 4; ++m)
#pragma unroll
      for (int n = 0; n < 4; ++n)
        acc[m][n] = __builtin_amdgcn_mfma_f32_16x16x32_bf16(af[m], bfv[n], acc[m][n], 0, 0, 0);
    __builtin_amdgcn_s_setprio(0);
    __builtin_amdgcn_s_barrier();

    // phase 2: M-half 1 (B frags reused from registers)
    bf16x8 af2[4];
#pragma unroll
    for (int m = 0; m < 4; ++m)
      af2[m] = *(const bf16x8*)(bq + abase + (4 + m) * 1024);
    if (t + 2 < NT) {
#pragma unroll
      for (int u = 0; u < 2; ++u)
        gload_lds16(bsrc[u] + (t + 2) * BK, smem + qs * 32768 + 16384 + u * 8192 + wave * 1024);
    }
    // counted wait: everything except tile t+2's 4 loads has landed => tile t+1 resident
    if (t < NT - 2)       { asm volatile("s_waitcnt vmcnt(4)" ::: "memory"); }
    else if (t == NT - 2) { asm volatile("s_waitcnt vmcnt(0)" ::: "memory"); }
    __builtin_amdgcn_s_barrier();
    __builtin_amdgcn_s_setprio(1);
#pragma unroll
    for (int m = 0; m < 4; ++m)
#pragma unroll
      for (int n = 0; n < 4; ++n)
        acc[4 + m][n] = __builtin_amdgcn_mfma_f32_16x16x32_bf16(af2[m], bfv[n], acc[4 + m][n], 0, 0, 0);
    __builtin_amdgcn_s_setprio(0);
    __builtin_amdgcn_s_barrier();
  }

  // ---- epilogue: per-wave LDS transpose -> coalesced dwordx4 stores.
  // C/D frag layout: col = lane&15, row = (lane>>4)*4 + reg.
  // Uses smem bytes [0, 34816) = buffers 0/1 region; tiles 20/21 reads retired
  // >= 4 barriers ago, and the final loop barrier orders all waves.
  const int ccol = lane & 15;
  const int quad = lane >> 4;
  float bv[4];
#pragma unroll
  for (int n = 0; n < 4; ++n)
    bv[n] = bias[tile_n + wn * 64 + n * 16 + ccol];

  float* tr = (float*)smem + wave * 1088;   // 16 rows x 68 floats (pad 4)
  const int erow = lane >> 2;   // 0..15
  const int es   = lane & 3;    // 16-float segment within the 64-col row

#pragma unroll
  for (int m = 0; m < 8; ++m) {
#pragma unroll
    for (int n = 0; n < 4; ++n)
#pragma unroll
      for (int r = 0; r < 4; ++r)
        tr[(quad * 4 + r) * 68 + n * 16 + ccol] = acc[m][n][r] + bv[n];
    // same-wave DS ops are in-order; no barrier needed (per-wave private region)
    const int grow = tile_m + wm * 128 + m * 16 + erow;
    if (grow < M_DIM) {
      float* dst = C + (size_t)grow * N_DIM + tile_n + wn * 64;
#pragma unroll
      for (int u = 0; u < 4; ++u)   // inst u: 16 rows x 64B contiguous segments
        *(f32x4*)(dst + u * 16 + es * 4) = *(const f32x4*)(tr + erow * 68 + u * 16 + es * 4);
    }
  }
}

extern "C" void kernel_launch(void* const* d_in, const int* in_sizes, int n_in,
                              void* d_out, int out_size, void* d_ws, size_t ws_size,
                              hipStream_t stream) {
  const float* x    = (const float*)d_in[0];
  const float* w    = (const float*)d_in[1];
  const float* bias = (const float*)d_in[2];
  float* out = (float*)d_out;

  __hip_bfloat16* xb = (__hip_bfloat16*)d_ws;                  // [M_PAD][K]
  __hip_bfloat16* wb = xb + (size_t)M_PAD * K_DIM;             // [N][K]

  static bool attr_set = false;
  if (!attr_set) {
    hipFuncSetAttribute(reinterpret_cast<const void*>(gemm_8p),
                        hipFuncAttributeMaxDynamicSharedMemorySize, 131072);
    attr_set = true;
  }

  cvt_fused<<<GX + GW, 256, 0, stream>>>(x, w, xb, wb);
  gemm_8p<<<NWG, 512, 131072, stream>>>(xb, wb, bias, out);
}